// Round 10
// baseline (124.227 us; speedup 1.0000x reference)
//
#include <hip/hip_runtime.h>
#include <hip/hip_bf16.h>

#define BATCH 16
#define NNODE 2000
#define HDIM  128
#define KNN   5
#define NROWS (BATCH * NNODE)   // 32000
#define LN_EPS 1e-5f

typedef __attribute__((ext_vector_type(8))) short short8;
typedef __attribute__((ext_vector_type(4))) float f32x4;

// ---------------------------------------------------------------------------
// Kernel 0: pre-convert Ws (3 x 128 x 128 fp32) into bf16 laid out in MFMA
// B-fragment order: entry f = (((wv*2+ct)*4+ks)*64+lane) of layer l holds
// W[l][col][k0..k0+7] with col = wv*32+ct*16+(lane&15), k0 = ks*32+(lane>>4)*8.
// ---------------------------------------------------------------------------
__global__ __launch_bounds__(256) void prep_w_kernel(
    const float* __restrict__ Ws, __hip_bfloat16* __restrict__ WB)
{
    int t = blockIdx.x * 256 + threadIdx.x;     // 3*2048 short8 entries
    if (t >= 3 * 2048) return;
    int l    = t >> 11;
    int r    = t & 2047;
    int lane = r & 63;
    int ks   = (r >> 6) & 3;
    int ct   = (r >> 8) & 1;
    int wv   = (r >> 9) & 3;
    int col  = wv * 32 + ct * 16 + (lane & 15);
    int k0   = ks * 32 + (lane >> 4) * 8;
    const float* src = Ws + ((size_t)l << 14) + col * HDIM + k0;
    __hip_bfloat16* dst = WB + ((size_t)t << 3);
    #pragma unroll
    for (int e = 0; e < 8; ++e) dst[e] = __float2bfloat16(src[e]);
}

__device__ __forceinline__ unsigned long long pack_di(float v, unsigned int idx) {
    unsigned int b = __float_as_uint(v);
    b = (b & 0x80000000u) ? ~b : (b | 0x80000000u);   // order-preserving
    return ((unsigned long long)b << 32) | idx;
}

// ---------------------------------------------------------------------------
// Kernel A: fused knn + layer 1.
// Block = 4 waves, 16 consecutive nodes (XCD-swizzled). Phase 1: each wave
// computes top-5+softmax for 4 rows (batched 8-deep float4 loads; HBM-bound,
// 128 KB contiguous dist per block); weights -> LDS + global (for layers 2,3).
// Phase 2: the MFMA layer body runs under other blocks' knn HBM time.
// ---------------------------------------------------------------------------
__global__ __launch_bounds__(256) void fused_knn_layer1_kernel(
    const float* __restrict__ dist,
    const float* __restrict__ h_in,          // node_emb
    const __hip_bfloat16* __restrict__ WB0,  // layer-0 fragments
    const float* __restrict__ bias,
    const float* __restrict__ gamma,
    const float* __restrict__ beta,
    int*   __restrict__ w_idx,
    float* __restrict__ w_val,
    float* __restrict__ h_out)
{
    __shared__ __hip_bfloat16 aggb[16][HDIM];   // 4 KB
    __shared__ float hown[16][HDIM];            // 8 KB (residual staging)
    __shared__ int   sidx[16][KNN];
    __shared__ float sw[16][KNN];
    __shared__ float wred[4][16][2];

    int tid = threadIdx.x;
    int wv  = tid >> 6;
    int l   = tid & 63;

    // XCD swizzle: 2000 blocks = 8 XCDs x 250; 2 batches per XCD.
    int bid = blockIdx.x;
    int x   = bid & 7;
    int j   = bid >> 3;
    int hi  = (j >= 125);
    int bsw = 2 * x + hi;
    int gid = bsw * 125 + (j - hi * 125);

    int node0 = gid * 16;
    size_t hbase = (size_t)bsw * NNODE * HDIM;

    // ---- Phase 1: knn for rows node0 + wv*4 + {0..3}
    for (int rr = 0; rr < 4; ++rr) {
        int m   = wv * 4 + rr;
        int row = node0 + m;
        const float4* r4 = reinterpret_cast<const float4*>(dist + (size_t)row * NNODE);

        unsigned long long pk0=~0ull, pk1=~0ull, pk2=~0ull, pk3=~0ull, pk4=~0ull;
        auto ins = [&](float d, int mm) {
            unsigned long long key = pack_di(d, (unsigned int)mm);
            if (key < pk4) {
                pk4 = key;
                unsigned long long t;
                if (pk4 < pk3) { t = pk3; pk3 = pk4; pk4 = t; }
                if (pk3 < pk2) { t = pk2; pk2 = pk3; pk3 = t; }
                if (pk2 < pk1) { t = pk1; pk1 = pk2; pk2 = t; }
                if (pk1 < pk0) { t = pk0; pk0 = pk1; pk1 = t; }
            }
        };

        float4 v[8];
        int base7 = l + 448;
        bool has8 = base7 < (NNODE / 4);
        #pragma unroll
        for (int i = 0; i < 7; ++i) v[i] = r4[l + 64 * i];
        v[7] = r4[has8 ? base7 : l];

        #pragma unroll
        for (int i = 0; i < 7; ++i) {
            int base = (l + 64 * i) * 4;
            ins(v[i].x, base); ins(v[i].y, base + 1);
            ins(v[i].z, base + 2); ins(v[i].w, base + 3);
        }
        if (has8) {
            int base = base7 * 4;
            ins(v[7].x, base); ins(v[7].y, base + 1);
            ins(v[7].z, base + 2); ins(v[7].w, base + 3);
        }

        unsigned long long chosen[KNN];
        #pragma unroll
        for (int r = 0; r < KNN; ++r) {
            unsigned long long mn = pk0;
            #pragma unroll
            for (int off = 32; off; off >>= 1) {
                unsigned long long o = __shfl_xor(mn, off, 64);
                if (o < mn) mn = o;
            }
            if (pk0 == mn) { pk0 = pk1; pk1 = pk2; pk2 = pk3; pk3 = pk4; pk4 = ~0ull; }
            chosen[r] = mn;
        }

        if (l == 0) {
            float d[KNN]; int ix[KNN];
            #pragma unroll
            for (int r = 0; r < KNN; ++r) {
                unsigned int ub = (unsigned int)(chosen[r] >> 32);
                ub = (ub & 0x80000000u) ? (ub ^ 0x80000000u) : ~ub;
                d[r]  = __uint_as_float(ub);
                ix[r] = (int)(chosen[r] & 0xffffffffu);
            }
            float e[KNN]; float sum = 0.f;
            #pragma unroll
            for (int r = 0; r < KNN; ++r) { e[r] = expf(d[0] - d[r]); sum += e[r]; }
            float inv = 1.f / sum;
            #pragma unroll
            for (int r = 0; r < KNN; ++r) {
                float wt = e[r] * inv;
                sidx[m][r] = ix[r];
                sw[m][r]   = wt;
                w_idx[row * KNN + r] = ix[r];
                w_val[row * KNN + r] = wt;
            }
        }
    }
    __syncthreads();

    // ---- Phase 2: layer 1 body
    const short8* wb = reinterpret_cast<const short8*>(WB0);
    short8 bfrag[2][4];
    #pragma unroll
    for (int ct = 0; ct < 2; ++ct)
        #pragma unroll
        for (int ks = 0; ks < 4; ++ks)
            bfrag[ct][ks] = wb[((wv * 2 + ct) * 4 + ks) * 64 + l];

    {
        int m  = tid >> 4;
        int c0 = (tid & 15) * 8;
        // own-row residual staging (coalesced float4)
        const float4* po = reinterpret_cast<const float4*>(
            h_in + (size_t)(node0 + m) * HDIM + c0);
        float4 o0 = po[0], o1 = po[1];
        *reinterpret_cast<float4*>(&hown[m][c0])     = o0;
        *reinterpret_cast<float4*>(&hown[m][c0 + 4]) = o1;

        float a0=0,a1=0,a2=0,a3=0,a4=0,a5=0,a6=0,a7=0;
        #pragma unroll
        for (int k = 0; k < KNN; ++k) {
            float wk = sw[m][k];
            const float4* p = reinterpret_cast<const float4*>(
                h_in + hbase + (size_t)sidx[m][k] * HDIM + c0);
            float4 v0 = p[0], v1 = p[1];
            a0 = fmaf(wk, v0.x, a0); a1 = fmaf(wk, v0.y, a1);
            a2 = fmaf(wk, v0.z, a2); a3 = fmaf(wk, v0.w, a3);
            a4 = fmaf(wk, v1.x, a4); a5 = fmaf(wk, v1.y, a5);
            a6 = fmaf(wk, v1.z, a6); a7 = fmaf(wk, v1.w, a7);
        }
        float vv[8] = {a0,a1,a2,a3,a4,a5,a6,a7};
        short8 pk;
        #pragma unroll
        for (int e = 0; e < 8; ++e) {
            __hip_bfloat16 hb = __float2bfloat16(vv[e]);
            pk[e] = *reinterpret_cast<short*>(&hb);
        }
        *reinterpret_cast<short8*>(&aggb[m][c0]) = pk;
    }
    __syncthreads();

    f32x4 acc0 = {0.f,0.f,0.f,0.f}, acc1 = {0.f,0.f,0.f,0.f};
    #pragma unroll
    for (int ks = 0; ks < 4; ++ks) {
        short8 afrag = *reinterpret_cast<const short8*>(&aggb[l & 15][ks * 32 + (l >> 4) * 8]);
        acc0 = __builtin_amdgcn_mfma_f32_16x16x32_bf16(afrag, bfrag[0][ks], acc0, 0, 0, 0);
        acc1 = __builtin_amdgcn_mfma_f32_16x16x32_bf16(afrag, bfrag[1][ks], acc1, 0, 0, 0);
    }

    int g = l >> 4;
    int col0 = wv * 32 + (l & 15);
    int col1 = col0 + 16;
    float b0  = bias[col0],  b1  = bias[col1];
    float gm0 = gamma[col0], gm1 = gamma[col1];
    float bt0 = beta[col0],  bt1 = beta[col1];

    float y0[4], y1[4];
    #pragma unroll
    for (int r = 0; r < 4; ++r) {
        int rl = g * 4 + r;
        y0[r] = hown[rl][col0] + fmaxf(acc0[r] + b0, 0.f);
        y1[r] = hown[rl][col1] + fmaxf(acc1[r] + b1, 0.f);
    }

    #pragma unroll
    for (int r = 0; r < 4; ++r) {
        float ss = y0[r] + y1[r];
        float qq = y0[r] * y0[r] + y1[r] * y1[r];
        #pragma unroll
        for (int off = 1; off < 16; off <<= 1) {
            ss += __shfl_xor(ss, off, 64);
            qq += __shfl_xor(qq, off, 64);
        }
        if ((l & 15) == 0) { wred[wv][g * 4 + r][0] = ss; wred[wv][g * 4 + r][1] = qq; }
    }
    __syncthreads();

    #pragma unroll
    for (int r = 0; r < 4; ++r) {
        int row = g * 4 + r;
        float S = wred[0][row][0] + wred[1][row][0] + wred[2][row][0] + wred[3][row][0];
        float Q = wred[0][row][1] + wred[1][row][1] + wred[2][row][1] + wred[3][row][1];
        float mu  = S * (1.f / 128.f);
        float var = Q * (1.f / 128.f) - mu * mu;
        float rs  = rsqrtf(var + LN_EPS);
        size_t orow = (size_t)(node0 + row) * HDIM;
        h_out[orow + col0] = (y0[r] - mu) * rs * gm0 + bt0;
        h_out[orow + col1] = (y1[r] - mu) * rs * gm1 + bt1;
    }
}

// ---------------------------------------------------------------------------
// Kernel B: layers 2,3 (same as before + LDS residual staging).
// ---------------------------------------------------------------------------
__global__ __launch_bounds__(256) void layer_kernel(
    const float* __restrict__ h_in,
    const int*   __restrict__ w_idx,
    const float* __restrict__ w_val,
    const __hip_bfloat16* __restrict__ WB,
    const float* __restrict__ bias,
    const float* __restrict__ gamma,
    const float* __restrict__ beta,
    float* __restrict__ h_out)
{
    __shared__ __hip_bfloat16 aggb[16][HDIM];
    __shared__ float hown[16][HDIM];
    __shared__ int   sidx[16][KNN];
    __shared__ float sw[16][KNN];
    __shared__ float wred[4][16][2];

    int tid = threadIdx.x;
    int wv  = tid >> 6;
    int l   = tid & 63;

    int bid = blockIdx.x;
    int x   = bid & 7;
    int j   = bid >> 3;
    int hi  = (j >= 125);
    int bsw = 2 * x + hi;
    int gid = bsw * 125 + (j - hi * 125);

    int node0 = gid * 16;
    size_t hbase = (size_t)bsw * NNODE * HDIM;

    const short8* wb = reinterpret_cast<const short8*>(WB);
    short8 bfrag[2][4];
    #pragma unroll
    for (int ct = 0; ct < 2; ++ct)
        #pragma unroll
        for (int ks = 0; ks < 4; ++ks)
            bfrag[ct][ks] = wb[((wv * 2 + ct) * 4 + ks) * 64 + l];

    if (tid < 16 * KNN) {
        int m = tid / KNN, k = tid % KNN;
        sidx[m][k] = w_idx[(node0 + m) * KNN + k];
        sw[m][k]   = w_val[(node0 + m) * KNN + k];
    }
    __syncthreads();

    {
        int m  = tid >> 4;
        int c0 = (tid & 15) * 8;
        const float4* po = reinterpret_cast<const float4*>(
            h_in + (size_t)(node0 + m) * HDIM + c0);
        float4 o0 = po[0], o1 = po[1];
        *reinterpret_cast<float4*>(&hown[m][c0])     = o0;
        *reinterpret_cast<float4*>(&hown[m][c0 + 4]) = o1;

        float a0=0,a1=0,a2=0,a3=0,a4=0,a5=0,a6=0,a7=0;
        #pragma unroll
        for (int k = 0; k < KNN; ++k) {
            float wk = sw[m][k];
            const float4* p = reinterpret_cast<const float4*>(
                h_in + hbase + (size_t)sidx[m][k] * HDIM + c0);
            float4 v0 = p[0], v1 = p[1];
            a0 = fmaf(wk, v0.x, a0); a1 = fmaf(wk, v0.y, a1);
            a2 = fmaf(wk, v0.z, a2); a3 = fmaf(wk, v0.w, a3);
            a4 = fmaf(wk, v1.x, a4); a5 = fmaf(wk, v1.y, a5);
            a6 = fmaf(wk, v1.z, a6); a7 = fmaf(wk, v1.w, a7);
        }
        float vv[8] = {a0,a1,a2,a3,a4,a5,a6,a7};
        short8 pk;
        #pragma unroll
        for (int e = 0; e < 8; ++e) {
            __hip_bfloat16 hb = __float2bfloat16(vv[e]);
            pk[e] = *reinterpret_cast<short*>(&hb);
        }
        *reinterpret_cast<short8*>(&aggb[m][c0]) = pk;
    }
    __syncthreads();

    f32x4 acc0 = {0.f,0.f,0.f,0.f}, acc1 = {0.f,0.f,0.f,0.f};
    #pragma unroll
    for (int ks = 0; ks < 4; ++ks) {
        short8 afrag = *reinterpret_cast<const short8*>(&aggb[l & 15][ks * 32 + (l >> 4) * 8]);
        acc0 = __builtin_amdgcn_mfma_f32_16x16x32_bf16(afrag, bfrag[0][ks], acc0, 0, 0, 0);
        acc1 = __builtin_amdgcn_mfma_f32_16x16x32_bf16(afrag, bfrag[1][ks], acc1, 0, 0, 0);
    }

    int g = l >> 4;
    int col0 = wv * 32 + (l & 15);
    int col1 = col0 + 16;
    float b0  = bias[col0],  b1  = bias[col1];
    float gm0 = gamma[col0], gm1 = gamma[col1];
    float bt0 = beta[col0],  bt1 = beta[col1];

    float y0[4], y1[4];
    #pragma unroll
    for (int r = 0; r < 4; ++r) {
        int rl = g * 4 + r;
        y0[r] = hown[rl][col0] + fmaxf(acc0[r] + b0, 0.f);
        y1[r] = hown[rl][col1] + fmaxf(acc1[r] + b1, 0.f);
    }

    #pragma unroll
    for (int r = 0; r < 4; ++r) {
        float ss = y0[r] + y1[r];
        float qq = y0[r] * y0[r] + y1[r] * y1[r];
        #pragma unroll
        for (int off = 1; off < 16; off <<= 1) {
            ss += __shfl_xor(ss, off, 64);
            qq += __shfl_xor(qq, off, 64);
        }
        if ((l & 15) == 0) { wred[wv][g * 4 + r][0] = ss; wred[wv][g * 4 + r][1] = qq; }
    }
    __syncthreads();

    #pragma unroll
    for (int r = 0; r < 4; ++r) {
        int row = g * 4 + r;
        float S = wred[0][row][0] + wred[1][row][0] + wred[2][row][0] + wred[3][row][0];
        float Q = wred[0][row][1] + wred[1][row][1] + wred[2][row][1] + wred[3][row][1];
        float mu  = S * (1.f / 128.f);
        float var = Q * (1.f / 128.f) - mu * mu;
        float rs  = rsqrtf(var + LN_EPS);
        size_t orow = (size_t)(node0 + row) * HDIM;
        h_out[orow + col0] = (y0[r] - mu) * rs * gm0 + bt0;
        h_out[orow + col1] = (y1[r] - mu) * rs * gm1 + bt1;
    }
}

// ---------------------------------------------------------------------------
extern "C" void kernel_launch(void* const* d_in, const int* in_sizes, int n_in,
                              void* d_out, int out_size, void* d_ws, size_t ws_size,
                              hipStream_t stream) {
    const float* node_emb = (const float*)d_in[0];
    const float* dist     = (const float*)d_in[1];
    const float* Ws       = (const float*)d_in[2];
    const float* bs       = (const float*)d_in[3];
    const float* gammas   = (const float*)d_in[4];
    const float* betas    = (const float*)d_in[5];
    float* out = (float*)d_out;

    char* ws = (char*)d_ws;
    int*   w_idx = (int*)  (ws + 0);                      // 640000 B
    float* w_val = (float*)(ws + 640000);                 // 640000 B
    __hip_bfloat16* WB = (__hip_bfloat16*)(ws + 1280000); // 3*32768 = 98304 B
    float* h_mid = (float*)(ws + 1378304);                // 16384000 B

    prep_w_kernel<<<24, 256, 0, stream>>>(Ws, WB);

    const int nblocks = NROWS / 16;   // 2000
    const int WL = 16384;             // bf16 elements per layer in WB

    fused_knn_layer1_kernel<<<nblocks, 256, 0, stream>>>(
        dist, node_emb, WB, bs, gammas, betas, w_idx, w_val, out);

    layer_kernel<<<nblocks, 256, 0, stream>>>(out,   w_idx, w_val,
        WB + WL,   bs + HDIM,   gammas + HDIM,   betas + HDIM,   h_mid);
    layer_kernel<<<nblocks, 256, 0, stream>>>(h_mid, w_idx, w_val,
        WB + 2*WL, bs + 2*HDIM, gammas + 2*HDIM, betas + 2*HDIM, out);
}

// Round 12
// 102.304 us; speedup vs baseline: 1.2143x; 1.2143x over previous
//
#include <hip/hip_runtime.h>
#include <hip/hip_bf16.h>

#define BATCH 16
#define NNODE 2000
#define HDIM  128
#define KNN   5
#define NROWS (BATCH * NNODE)   // 32000
#define LN_EPS 1e-5f

typedef __attribute__((ext_vector_type(8))) short short8;
typedef __attribute__((ext_vector_type(4))) float f32x4;

__device__ __forceinline__ float b2f(short s) {
    unsigned int u = ((unsigned int)(unsigned short)s) << 16;
    return __uint_as_float(u);
}
__device__ __forceinline__ short f2b(float f) {
    __hip_bfloat16 h = __float2bfloat16(f);
    return *reinterpret_cast<short*>(&h);
}

__device__ __forceinline__ unsigned long long pack_di(float v, unsigned int idx) {
    unsigned int b = __float_as_uint(v);
    b = (b & 0x80000000u) ? ~b : (b | 0x80000000u);   // order-preserving
    return ((unsigned long long)b << 32) | idx;
}

// ---------------------------------------------------------------------------
// Kernel 1: knn + softmax (8000 blocks, one wave per row), with two folded
// preps: (a) Ws -> bf16 MFMA B-fragment order WB (blocks 0..23);
// (b) node_emb fp32 -> bf16 hb (blocks 0..1999, 8 elems/thread).
// knn: all 8 row-slice float4 loads issued up front (HBM-BW-bound).
// ---------------------------------------------------------------------------
__global__ __launch_bounds__(256) void knn_prep_kernel(
    const float* __restrict__ dist,
    const float* __restrict__ Ws,
    const float* __restrict__ node_emb,
    __hip_bfloat16* __restrict__ WB,
    short* __restrict__ hb,             // bf16 node_emb
    int* __restrict__ w_idx,
    float* __restrict__ w_val)
{
    int tg = blockIdx.x * 256 + threadIdx.x;

    // ---- (a) weight prep: 6144 short8 entries
    if (tg < 3 * 2048) {
        int l    = tg >> 11;
        int r    = tg & 2047;
        int lane = r & 63;
        int ks   = (r >> 6) & 3;
        int ct   = (r >> 8) & 1;
        int wv   = (r >> 9) & 3;
        int col  = wv * 32 + ct * 16 + (lane & 15);
        int k0   = ks * 32 + (lane >> 4) * 8;
        const float* src = Ws + ((size_t)l << 14) + col * HDIM + k0;
        __hip_bfloat16* dst = WB + ((size_t)tg << 3);
        #pragma unroll
        for (int e = 0; e < 8; ++e) dst[e] = __float2bfloat16(src[e]);
    }

    // ---- (b) node_emb -> bf16: 512000 groups of 8
    if (tg < NROWS * HDIM / 8) {
        const float4* src = reinterpret_cast<const float4*>(node_emb) + tg * 2;
        float4 a = src[0], bq = src[1];
        short8 pk;
        pk[0]=f2b(a.x); pk[1]=f2b(a.y); pk[2]=f2b(a.z); pk[3]=f2b(a.w);
        pk[4]=f2b(bq.x); pk[5]=f2b(bq.y); pk[6]=f2b(bq.z); pk[7]=f2b(bq.w);
        *reinterpret_cast<short8*>(hb + (size_t)tg * 8) = pk;
    }

    // ---- knn for this wave's row
    int row  = blockIdx.x * 4 + (threadIdx.x >> 6);
    int lane = threadIdx.x & 63;
    const float4* r4 = reinterpret_cast<const float4*>(dist + (size_t)row * NNODE);

    unsigned long long pk0 = ~0ull, pk1 = ~0ull, pk2 = ~0ull, pk3 = ~0ull, pk4 = ~0ull;

    auto ins = [&](float d, int m) {
        unsigned long long key = pack_di(d, (unsigned int)m);
        if (key < pk4) {
            pk4 = key;
            unsigned long long t;
            if (pk4 < pk3) { t = pk3; pk3 = pk4; pk4 = t; }
            if (pk3 < pk2) { t = pk2; pk2 = pk3; pk3 = t; }
            if (pk2 < pk1) { t = pk1; pk1 = pk2; pk2 = t; }
            if (pk1 < pk0) { t = pk0; pk0 = pk1; pk1 = t; }
        }
    };

    float4 v[8];
    int base7 = lane + 448;
    bool has8 = base7 < (NNODE / 4);
    #pragma unroll
    for (int i = 0; i < 7; ++i) v[i] = r4[lane + 64 * i];
    v[7] = r4[has8 ? base7 : lane];

    #pragma unroll
    for (int i = 0; i < 7; ++i) {
        int base = (lane + 64 * i) * 4;
        ins(v[i].x, base); ins(v[i].y, base + 1);
        ins(v[i].z, base + 2); ins(v[i].w, base + 3);
    }
    if (has8) {
        int base = base7 * 4;
        ins(v[7].x, base); ins(v[7].y, base + 1);
        ins(v[7].z, base + 2); ins(v[7].w, base + 3);
    }

    unsigned long long chosen[KNN];
    #pragma unroll
    for (int r = 0; r < KNN; ++r) {
        unsigned long long mn = pk0;
        #pragma unroll
        for (int off = 32; off; off >>= 1) {
            unsigned long long o = __shfl_xor(mn, off, 64);
            if (o < mn) mn = o;
        }
        if (pk0 == mn) { pk0 = pk1; pk1 = pk2; pk2 = pk3; pk3 = pk4; pk4 = ~0ull; }
        chosen[r] = mn;
    }

    if (lane == 0) {
        float d[KNN]; int ix[KNN];
        #pragma unroll
        for (int r = 0; r < KNN; ++r) {
            unsigned int ub = (unsigned int)(chosen[r] >> 32);
            ub = (ub & 0x80000000u) ? (ub ^ 0x80000000u) : ~ub;
            d[r]  = __uint_as_float(ub);
            ix[r] = (int)(chosen[r] & 0xffffffffu);
        }
        float e[KNN]; float sum = 0.f;
        #pragma unroll
        for (int r = 0; r < KNN; ++r) { e[r] = expf(d[0] - d[r]); sum += e[r]; }
        float inv = 1.f / sum;
        #pragma unroll
        for (int r = 0; r < KNN; ++r) {
            w_idx[row * KNN + r] = ix[r];
            w_val[row * KNN + r] = e[r] * inv;
        }
    }
}

// ---------------------------------------------------------------------------
// Kernel 2: one GCN layer via MFMA, bf16 h storage.
// Block = 4 waves, 16 consecutive nodes (XCD-swizzled). bf16 gathers (one
// short8/neighbor), fp32 agg math -> bf16 agg LDS; 8x mfma_16x16x32_bf16 per
// wave; fp32 ReLU+residual+LN; output bf16 (intermediate) or fp32 (final).
// ---------------------------------------------------------------------------
template<bool OUT_F32>
__global__ __launch_bounds__(256) void layer_kernel_b(
    const short* __restrict__ hin,           // bf16 h
    const int*   __restrict__ w_idx,
    const float* __restrict__ w_val,
    const __hip_bfloat16* __restrict__ WB,   // fragment-ordered, this layer
    const float* __restrict__ bias,
    const float* __restrict__ gamma,
    const float* __restrict__ beta,
    short* __restrict__ hout_b,
    float* __restrict__ hout_f)
{
    __shared__ __hip_bfloat16 aggb[16][HDIM];   // 4 KB
    __shared__ short hown[16][HDIM];            // 4 KB (bf16 residual staging)
    __shared__ int   sidx[16][KNN];
    __shared__ float sw[16][KNN];
    __shared__ float wred[4][16][2];

    int tid = threadIdx.x;
    int wv  = tid >> 6;
    int l   = tid & 63;

    // XCD swizzle: 2000 blocks = 8 XCDs x 250; 2 batches per XCD.
    int bid = blockIdx.x;
    int x   = bid & 7;
    int j   = bid >> 3;
    int hi  = (j >= 125);
    int bsw = 2 * x + hi;
    int gid = bsw * 125 + (j - hi * 125);

    int node0 = gid * 16;
    size_t hbase = (size_t)bsw * NNODE * HDIM;

    // ---- B fragments: 8 coalesced short8 loads
    const short8* wb = reinterpret_cast<const short8*>(WB);
    short8 bfrag[2][4];
    #pragma unroll
    for (int ct = 0; ct < 2; ++ct)
        #pragma unroll
        for (int ks = 0; ks < 4; ++ks)
            bfrag[ct][ks] = wb[((wv * 2 + ct) * 4 + ks) * 64 + l];

    if (tid < 16 * KNN) {
        int m = tid / KNN, k = tid % KNN;
        sidx[m][k] = w_idx[(node0 + m) * KNN + k];
        sw[m][k]   = w_val[(node0 + m) * KNN + k];
    }
    __syncthreads();

    // ---- aggregation: thread t -> node m = t>>4, cols c0 = (t&15)*8
    {
        int m  = tid >> 4;
        int c0 = (tid & 15) * 8;
        // own-row residual staging (one 16B load)
        short8 own = *reinterpret_cast<const short8*>(
            hin + (size_t)(node0 + m) * HDIM + c0);
        *reinterpret_cast<short8*>(&hown[m][c0]) = own;

        float a0=0,a1=0,a2=0,a3=0,a4=0,a5=0,a6=0,a7=0;
        #pragma unroll
        for (int k = 0; k < KNN; ++k) {
            float wk = sw[m][k];
            short8 hv = *reinterpret_cast<const short8*>(
                hin + hbase + (size_t)sidx[m][k] * HDIM + c0);
            a0 = fmaf(wk, b2f(hv[0]), a0); a1 = fmaf(wk, b2f(hv[1]), a1);
            a2 = fmaf(wk, b2f(hv[2]), a2); a3 = fmaf(wk, b2f(hv[3]), a3);
            a4 = fmaf(wk, b2f(hv[4]), a4); a5 = fmaf(wk, b2f(hv[5]), a5);
            a6 = fmaf(wk, b2f(hv[6]), a6); a7 = fmaf(wk, b2f(hv[7]), a7);
        }
        short8 pk;
        pk[0]=f2b(a0); pk[1]=f2b(a1); pk[2]=f2b(a2); pk[3]=f2b(a3);
        pk[4]=f2b(a4); pk[5]=f2b(a5); pk[6]=f2b(a6); pk[7]=f2b(a7);
        *reinterpret_cast<short8*>(&aggb[tid >> 4][c0]) = pk;
    }
    __syncthreads();

    // ---- MFMA: per wave, C(16x32) over 4 k-steps
    f32x4 acc0 = {0.f,0.f,0.f,0.f}, acc1 = {0.f,0.f,0.f,0.f};
    #pragma unroll
    for (int ks = 0; ks < 4; ++ks) {
        short8 afrag = *reinterpret_cast<const short8*>(&aggb[l & 15][ks * 32 + (l >> 4) * 8]);
        acc0 = __builtin_amdgcn_mfma_f32_16x16x32_bf16(afrag, bfrag[0][ks], acc0, 0, 0, 0);
        acc1 = __builtin_amdgcn_mfma_f32_16x16x32_bf16(afrag, bfrag[1][ks], acc1, 0, 0, 0);
    }

    // ---- epilogue: y = h + relu(C + bias); LN over 128 cols
    int g = l >> 4;
    int col0 = wv * 32 + (l & 15);
    int col1 = col0 + 16;
    float b0  = bias[col0],  b1  = bias[col1];
    float gm0 = gamma[col0], gm1 = gamma[col1];
    float bt0 = beta[col0],  bt1 = beta[col1];

    float y0[4], y1[4];
    #pragma unroll
    for (int r = 0; r < 4; ++r) {
        int rl = g * 4 + r;
        y0[r] = b2f(hown[rl][col0]) + fmaxf(acc0[r] + b0, 0.f);
        y1[r] = b2f(hown[rl][col1]) + fmaxf(acc1[r] + b1, 0.f);
    }

    #pragma unroll
    for (int r = 0; r < 4; ++r) {
        float ss = y0[r] + y1[r];
        float qq = y0[r] * y0[r] + y1[r] * y1[r];
        #pragma unroll
        for (int off = 1; off < 16; off <<= 1) {
            ss += __shfl_xor(ss, off, 64);
            qq += __shfl_xor(qq, off, 64);
        }
        if ((l & 15) == 0) { wred[wv][g * 4 + r][0] = ss; wred[wv][g * 4 + r][1] = qq; }
    }
    __syncthreads();

    #pragma unroll
    for (int r = 0; r < 4; ++r) {
        int row = g * 4 + r;
        float S = wred[0][row][0] + wred[1][row][0] + wred[2][row][0] + wred[3][row][0];
        float Q = wred[0][row][1] + wred[1][row][1] + wred[2][row][1] + wred[3][row][1];
        float mu  = S * (1.f / 128.f);
        float var = Q * (1.f / 128.f) - mu * mu;
        float rs  = rsqrtf(var + LN_EPS);
        size_t orow = (size_t)(node0 + row) * HDIM;
        float o0 = (y0[r] - mu) * rs * gm0 + bt0;
        float o1 = (y1[r] - mu) * rs * gm1 + bt1;
        if (OUT_F32) {
            hout_f[orow + col0] = o0;
            hout_f[orow + col1] = o1;
        } else {
            hout_b[orow + col0] = f2b(o0);
            hout_b[orow + col1] = f2b(o1);
        }
    }
}

// ---------------------------------------------------------------------------
extern "C" void kernel_launch(void* const* d_in, const int* in_sizes, int n_in,
                              void* d_out, int out_size, void* d_ws, size_t ws_size,
                              hipStream_t stream) {
    const float* node_emb = (const float*)d_in[0];
    const float* dist     = (const float*)d_in[1];
    const float* Ws       = (const float*)d_in[2];
    const float* bs       = (const float*)d_in[3];
    const float* gammas   = (const float*)d_in[4];
    const float* betas    = (const float*)d_in[5];
    float* out = (float*)d_out;

    char* ws = (char*)d_ws;
    int*   w_idx = (int*)  (ws + 0);                      // 640000 B
    float* w_val = (float*)(ws + 640000);                 // 640000 B
    __hip_bfloat16* WB = (__hip_bfloat16*)(ws + 1280000); // 98304 B
    short* hb  = (short*)(ws + 1378304);                  // 8192000 B (bf16 h0)
    short* h1b = (short*)(ws + 9570304);                  // 8192000 B
    short* h2b = (short*)(ws + 17762304);                 // 8192000 B

    // Dispatch 1: knn + weight prep + node_emb->bf16
    knn_prep_kernel<<<NROWS / 4, 256, 0, stream>>>(
        dist, Ws, node_emb, WB, hb, w_idx, w_val);

    const int nblocks = NROWS / 16;   // 2000
    const int WL = 16384;             // bf16 elements per layer in WB

    // Dispatches 2-4: three layers (bf16 intermediates, fp32 final out)
    layer_kernel_b<false><<<nblocks, 256, 0, stream>>>(hb,  w_idx, w_val,
        WB,        bs,          gammas,          betas,          h1b, nullptr);
    layer_kernel_b<false><<<nblocks, 256, 0, stream>>>(h1b, w_idx, w_val,
        WB + WL,   bs + HDIM,   gammas + HDIM,   betas + HDIM,   h2b, nullptr);
    layer_kernel_b<true><<<nblocks, 256, 0, stream>>>(h2b, w_idx, w_val,
        WB + 2*WL, bs + 2*HDIM, gammas + 2*HDIM, betas + 2*HDIM, nullptr, out);
}